// Round 8
// baseline (241.207 us; speedup 1.0000x reference)
//
#include <hip/hip_runtime.h>
#include <hip/hip_bf16.h>
#include <stdint.h>

// B=2, S=2048, D_MODEL=768, H=12, HD=64, 7*D=5376
typedef short short8 __attribute__((ext_vector_type(8)));
typedef float f32x4 __attribute__((ext_vector_type(4)));
typedef float f32x16 __attribute__((ext_vector_type(16)));
typedef unsigned short u16x4 __attribute__((ext_vector_type(4)));
typedef unsigned uint4v __attribute__((ext_vector_type(4)));

#define MFMA16 __builtin_amdgcn_mfma_f32_16x16x32_bf16
#define MFMA32 __builtin_amdgcn_mfma_f32_32x32x16_bf16

typedef unsigned int __attribute__((address_space(1))) as1_u32;
typedef unsigned int __attribute__((address_space(3))) as3_u32;
#define GLOAD16(gsrc, ldst) \
  __builtin_amdgcn_global_load_lds((const as1_u32*)(gsrc), (as3_u32*)(ldst), 16, 0, 0)

__device__ __forceinline__ unsigned short f2bf(float f) {
  __hip_bfloat16 h = __float2bfloat16(f);
  return *(unsigned short*)&h;
}
__device__ __forceinline__ unsigned pk2(float lo, float hi) {
  return ((unsigned)f2bf(hi) << 16) | (unsigned)f2bf(lo);
}
// vdst.row1 (lanes>=32) <-> vsrc.row0 (lanes<32)
__device__ __forceinline__ void plswap(unsigned &a, unsigned &b) {
  asm volatile("v_permlane32_swap_b32 %0, %1" : "+v"(a), "+v"(b));
}

// Build PV A-fragment for chunk kc2 from swapped-QK accumulator halves.
// acc[sn][reg] holds S^T[s = sn*32 + 8*(reg>>2) + 4*g5 + (reg&3)][t = l31].
__device__ __forceinline__ short8 pv_frag(const f32x16* acc, int kc2) {
  int n = kc2 >> 1, c = kc2 & 1;
  int o0 = 2 * c, o1 = 2 * c + 1;
  unsigned x0 = pk2(acc[n][o0 * 4 + 0], acc[n][o0 * 4 + 1]);
  unsigned x1 = pk2(acc[n][o0 * 4 + 2], acc[n][o0 * 4 + 3]);
  unsigned y0 = pk2(acc[n][o1 * 4 + 0], acc[n][o1 * 4 + 1]);
  unsigned y1 = pk2(acc[n][o1 * 4 + 2], acc[n][o1 * 4 + 3]);
  plswap(x0, y0);
  plswap(x1, y1);
  uint4v fu; fu.x = x0; fu.y = x1; fu.z = y0; fu.w = y1;
  return __builtin_bit_cast(short8, fu);
}

// ---------------- convert f32 -> bf16, 4 elems/thread ----------------
__global__ __launch_bounds__(256) void cvt_bf16_4(const float* __restrict__ in,
                                                  unsigned short* __restrict__ out,
                                                  int n) {
  int i = (blockIdx.x * 256 + threadIdx.x) * 4;
  if (i >= n) return;
  f32x4 v = *(const f32x4*)(in + i);
  u16x4 o;
  o.x = f2bf(v.x); o.y = f2bf(v.y); o.z = f2bf(v.z); o.w = f2bf(v.w);
  *(u16x4*)(out + i) = o;
}

// ---------------- 64x64 head-tile transpose: src[b][s][stride] -> dst[bh][d][2048] ----
__global__ __launch_bounds__(256) void transp64(const unsigned short* __restrict__ src,
                                                int stride, int off,
                                                unsigned short* __restrict__ dst) {
  __shared__ __align__(16) unsigned short t[64 * 64];
  const int tid = threadIdx.x;
  const int tt = blockIdx.x, bh = blockIdx.y;
  const int b = bh / 12, h = bh % 12;
  const unsigned short* sbase = src + (size_t)(b * 2048 + tt * 64) * stride + h * 64 + off;
  for (int it = 0; it < 2; ++it) {
    int slot = it * 256 + tid, s = slot >> 3, j = slot & 7;
    short8 v = *(const short8*)(sbase + (size_t)s * stride + j * 8);
    int phys = (s + 8 * j) & 63;
    for (int e = 0; e < 8; ++e)
      t[(j * 8 + e) * 64 + phys] = ((unsigned short*)&v)[e];
  }
  __syncthreads();
  unsigned short* dbase = dst + (size_t)bh * 64 * 2048 + tt * 64;
  for (int it = 0; it < 2; ++it) {
    int slot = it * 256 + tid, d = slot >> 3, c = slot & 7;
    int pc = (c + (d >> 3)) & 7;
    short8 v = *(const short8*)(t + d * 64 + pc * 8);
    *(short8*)(dbase + (size_t)d * 2048 + c * 8) = v;
  }
}

// ---------------- GEMM: C[M][N] = A[M][K] * B[N][K]^T + bias ----------------
template <bool OUT_BF16>
__global__ __launch_bounds__(256) void gemm_nt(const unsigned short* __restrict__ A,
                                               const unsigned short* __restrict__ Bm,
                                               const float* __restrict__ bias,
                                               void* __restrict__ Cout,
                                               int M, int N, int K) {
  __shared__ __align__(16) char smem[32768];
  char* As = smem;
  char* Bs = smem + 16384;
  const int tid = threadIdx.x;
  const int w = tid >> 6, l = tid & 63;
  const int wm = w >> 1, wn = w & 1;
  const int Row0 = blockIdx.y * 128, Col0 = blockIdx.x * 128;

  f32x4 z; z.x = 0.f; z.y = 0.f; z.z = 0.f; z.w = 0.f;
  f32x4 acc[4][4];
  for (int m = 0; m < 4; ++m)
    for (int n = 0; n < 4; ++n) acc[m][n] = z;

  for (int k0 = 0; k0 < K; k0 += 64) {
    for (int it = 0; it < 4; ++it) {
      int slot = it * 256 + tid;
      int row = slot >> 3, j = slot & 7;
      int gc = j ^ (row & 7);
      GLOAD16(A + (size_t)(Row0 + row) * K + k0 + gc * 8, As + slot * 16);
      GLOAD16(Bm + (size_t)(Col0 + row) * K + k0 + gc * 8, Bs + slot * 16);
    }
    __syncthreads();
    for (int kc = 0; kc < 2; ++kc) {
      int c = (l >> 4) + 4 * kc;
      short8 af[4], bf[4];
      for (int m = 0; m < 4; ++m) {
        int t = wm * 64 + m * 16 + (l & 15);
        af[m] = *(const short8*)(As + t * 128 + ((c ^ (t & 7)) * 16));
      }
      for (int n = 0; n < 4; ++n) {
        int t = wn * 64 + n * 16 + (l & 15);
        bf[n] = *(const short8*)(Bs + t * 128 + ((c ^ (t & 7)) * 16));
      }
      for (int m = 0; m < 4; ++m)
        for (int n = 0; n < 4; ++n)
          acc[m][n] = MFMA16(af[m], bf[n], acc[m][n], 0, 0, 0);
    }
    __syncthreads();
  }
  for (int n = 0; n < 4; ++n) {
    int col = Col0 + wn * 64 + n * 16 + (l & 15);
    float bv = bias[col];
    for (int m = 0; m < 4; ++m) {
      int rbase = Row0 + wm * 64 + m * 16 + (l >> 4) * 4;
      for (int r = 0; r < 4; ++r) {
        float v = acc[m][n][r] + bv;
        size_t idx = (size_t)(rbase + r) * N + col;
        if (OUT_BF16) ((unsigned short*)Cout)[idx] = f2bf(v);
        else          ((float*)Cout)[idx] = v;
      }
    }
  }
}

// ---------------- pass1: 2 waves (wave0: a1/t1 via q1, wave1: a2/t2 via q2) ----------
// 64 t-rows per block; grid (32 tt, 24 bh) = 768 blocks. Double-buffered staging.
__global__ __launch_bounds__(128) void pass1(const unsigned short* __restrict__ qkv,
                                             const unsigned short* __restrict__ vt,
                                             unsigned short* __restrict__ u) {
  __shared__ __align__(16) char smem[49152];   // 2 bufs x (K1 8K | K2 8K | V 8K)
  const int tid = threadIdx.x, w = tid >> 6, l = tid & 63;
  const int g5 = l >> 5, l31 = l & 31;
  const int tt = blockIdx.x, bh = blockIdx.y;
  const int b = bh / 12, h = bh % 12;
  const int matOff = (w == 0) ? 0 : 2 * 768;   // q1 / q2

  // Q fragments (B-operand): [tc][kc], col t = tc*32+l31, k-d = kc*16+g5*8
  short8 qf[2][4];
#pragma unroll
  for (int tc = 0; tc < 2; ++tc) {
    const unsigned short* qrow =
        qkv + (size_t)(b * 2048 + tt * 64 + tc * 32 + l31) * 5376 + h * 64 + matOff;
#pragma unroll
    for (int kc = 0; kc < 4; ++kc)
      qf[tc][kc] = *(const short8*)(qrow + kc * 16 + g5 * 8);
  }

  f32x16 z16;
#pragma unroll
  for (int i = 0; i < 16; ++i) z16[i] = 0.f;
  f32x16 tacc[2][2];   // [tc][dn]
  tacc[0][0] = z16; tacc[0][1] = z16; tacc[1][0] = z16; tacc[1][1] = z16;

  auto STAGE = [&](char* buf, int s0) {
#pragma unroll
    for (int c = 0; c < 4; ++c) {
      int r = c * 128 + tid, row = r >> 3, j = r & 7, gc = j ^ (row & 7);
      GLOAD16(qkv + (size_t)(b * 2048 + s0 + row) * 5376 + h * 64 + 1 * 768 + gc * 8,
              buf + r * 16);
    }
#pragma unroll
    for (int c = 0; c < 4; ++c) {
      int r = c * 128 + tid, row = r >> 3, j = r & 7, gc = j ^ (row & 7);
      GLOAD16(qkv + (size_t)(b * 2048 + s0 + row) * 5376 + h * 64 + 3 * 768 + gc * 8,
              buf + 8192 + r * 16);
    }
#pragma unroll
    for (int c = 0; c < 4; ++c) {
      int r = c * 128 + tid, row = r >> 3, j = r & 7, gc = j ^ (row & 7);
      GLOAD16(vt + (size_t)(bh * 64 + row) * 2048 + s0 + gc * 8, buf + 16384 + r * 16);
    }
  };

  STAGE(smem, 0);
  __syncthreads();
  for (int si = 0; si < 32; ++si) {
    char* cur = smem + (si & 1) * 24576;
    if (si < 31) STAGE(smem + ((si + 1) & 1) * 24576, (si + 1) * 64);
    const char* Ks = cur + w * 8192;
    const char* Vs = cur + 16384;

    f32x16 at[2][2];   // [tc][sn]
    at[0][0] = z16; at[0][1] = z16; at[1][0] = z16; at[1][1] = z16;
#pragma unroll
    for (int kc = 0; kc < 4; ++kc)
#pragma unroll
      for (int sn = 0; sn < 2; ++sn) {
        int srow = sn * 32 + l31;
        short8 kf = *(const short8*)(Ks + srow * 128 + (((kc * 2 + g5) ^ (l31 & 7)) * 16));
        at[0][sn] = MFMA32(kf, qf[0][kc], at[0][sn], 0, 0, 0);
        at[1][sn] = MFMA32(kf, qf[1][kc], at[1][sn], 0, 0, 0);
      }
#pragma unroll
    for (int kc2 = 0; kc2 < 4; ++kc2) {
      short8 pa0 = pv_frag(at[0], kc2);
      short8 pa1 = pv_frag(at[1], kc2);
#pragma unroll
      for (int dn = 0; dn < 2; ++dn) {
        int drow = dn * 32 + l31;
        short8 vf = *(const short8*)(Vs + drow * 128 + (((kc2 * 2 + g5) ^ (l31 & 7)) * 16));
        tacc[0][dn] = MFMA32(pa0, vf, tacc[0][dn], 0, 0, 0);
        tacc[1][dn] = MFMA32(pa1, vf, tacc[1][dn], 0, 0, 0);
      }
    }
    __syncthreads();
  }

  // combine: wave1 (t2) -> LDS, wave0 computes u = silu(t1)*t2
  float* exch = (float*)smem;
  if (w == 1) {
#pragma unroll
    for (int tc = 0; tc < 2; ++tc)
#pragma unroll
      for (int dn = 0; dn < 2; ++dn)
#pragma unroll
        for (int r = 0; r < 16; ++r) {
          int trow = tc * 32 + (r & 3) + 8 * (r >> 2) + 4 * g5;
          exch[trow * 64 + dn * 32 + l31] = tacc[tc][dn][r];
        }
  }
  __syncthreads();
  if (w == 0) {
#pragma unroll
    for (int tc = 0; tc < 2; ++tc)
#pragma unroll
      for (int dn = 0; dn < 2; ++dn)
#pragma unroll
        for (int r = 0; r < 16; ++r) {
          int crow = (r & 3) + 8 * (r >> 2) + 4 * g5;
          int t = tt * 64 + tc * 32 + crow;
          int d = dn * 32 + l31;
          float x1 = tacc[tc][dn][r];
          float x2 = exch[(tc * 32 + crow) * 64 + d];
          float uu = (x1 / (1.f + expf(-x1))) * x2;
          u[(size_t)(b * 2048 + t) * 768 + h * 64 + d] = f2bf(uu);
        }
  }
}

// ---------------- pass2: 2 waves, both full a3, PV split by d-half -----------------
// 64 t-rows per block; grid (32 tt, 24 bh) = 768 blocks. Double-buffered staging.
__global__ __launch_bounds__(128) void pass2(const unsigned short* __restrict__ qkv,
                                             const unsigned short* __restrict__ ut,
                                             float* __restrict__ ctx,
                                             float* __restrict__ partials) {
  __shared__ __align__(16) char smem[32768];   // 2 bufs x (K3 8K | U 8K)
  const int tid = threadIdx.x, w = tid >> 6, l = tid & 63;
  const int g5 = l >> 5, l31 = l & 31;
  const int tt = blockIdx.x, bh = blockIdx.y;
  const int b = bh / 12, h = bh % 12;

  short8 qf[2][4];
#pragma unroll
  for (int tc = 0; tc < 2; ++tc) {
    const unsigned short* qrow =
        qkv + (size_t)(b * 2048 + tt * 64 + tc * 32 + l31) * 5376 + h * 64 + 4 * 768;
#pragma unroll
    for (int kc = 0; kc < 4; ++kc)
      qf[tc][kc] = *(const short8*)(qrow + kc * 16 + g5 * 8);
  }

  f32x16 z16;
#pragma unroll
  for (int i = 0; i < 16; ++i) z16[i] = 0.f;
  f32x16 ca[2];   // [tc], d-half = w
  ca[0] = z16; ca[1] = z16;

  auto STAGE = [&](char* buf, int s0) {
#pragma unroll
    for (int c = 0; c < 4; ++c) {
      int r = c * 128 + tid, row = r >> 3, j = r & 7, gc = j ^ (row & 7);
      GLOAD16(qkv + (size_t)(b * 2048 + s0 + row) * 5376 + h * 64 + 5 * 768 + gc * 8,
              buf + r * 16);
    }
#pragma unroll
    for (int c = 0; c < 4; ++c) {
      int r = c * 128 + tid, row = r >> 3, j = r & 7, gc = j ^ (row & 7);
      GLOAD16(ut + (size_t)(bh * 64 + row) * 2048 + s0 + gc * 8, buf + 8192 + r * 16);
    }
  };

  STAGE(smem, 0);
  __syncthreads();
  for (int si = 0; si < 32; ++si) {
    char* cur = smem + (si & 1) * 16384;
    if (si < 31) STAGE(smem + ((si + 1) & 1) * 16384, (si + 1) * 64);
    const char* Ks = cur;
    const char* Us = cur + 8192;

    f32x16 at[2][2];
    at[0][0] = z16; at[0][1] = z16; at[1][0] = z16; at[1][1] = z16;
#pragma unroll
    for (int kc = 0; kc < 4; ++kc)
#pragma unroll
      for (int sn = 0; sn < 2; ++sn) {
        int srow = sn * 32 + l31;
        short8 kf = *(const short8*)(Ks + srow * 128 + (((kc * 2 + g5) ^ (l31 & 7)) * 16));
        at[0][sn] = MFMA32(kf, qf[0][kc], at[0][sn], 0, 0, 0);
        at[1][sn] = MFMA32(kf, qf[1][kc], at[1][sn], 0, 0, 0);
      }
#pragma unroll
    for (int kc2 = 0; kc2 < 4; ++kc2) {
      short8 pa0 = pv_frag(at[0], kc2);
      short8 pa1 = pv_frag(at[1], kc2);
      int drow = w * 32 + l31;
      short8 uf = *(const short8*)(Us + drow * 128 + (((kc2 * 2 + g5) ^ (l31 & 7)) * 16));
      ca[0] = MFMA32(pa0, uf, ca[0], 0, 0, 0);
      ca[1] = MFMA32(pa1, uf, ca[1], 0, 0, 0);
    }
    __syncthreads();
  }

  float psum = 0.f, psum2 = 0.f;
#pragma unroll
  for (int tc = 0; tc < 2; ++tc)
#pragma unroll
    for (int r = 0; r < 16; ++r) {
      int t = tt * 64 + tc * 32 + (r & 3) + 8 * (r >> 2) + 4 * g5;
      int d = w * 32 + l31;
      float v = ca[tc][r];
      ctx[(size_t)(b * 2048 + t) * 768 + h * 64 + d] = v;
      psum += v; psum2 += v * v;
    }

  float* red = (float*)smem;
  red[tid] = psum; red[128 + tid] = psum2;
  __syncthreads();
  for (int st = 64; st > 0; st >>= 1) {
    if (tid < st) {
      red[tid] += red[tid + st];
      red[128 + tid] += red[128 + tid + st];
    }
    __syncthreads();
  }
  if (tid == 0) {
    partials[(bh * 32 + tt) * 2] = red[0];
    partials[(bh * 32 + tt) * 2 + 1] = red[128];
  }
}

// ---------------- finalize GN stats from 32 partials per group ----------------
__global__ __launch_bounds__(64) void gn_finalize(const float* __restrict__ partials,
                                                  float* __restrict__ stats) {
  const int g = blockIdx.x;
  const int l = threadIdx.x;
  double s = 0.0, s2 = 0.0;
  if (l < 32) {
    s = (double)partials[(g * 32 + l) * 2];
    s2 = (double)partials[(g * 32 + l) * 2 + 1];
  }
  for (int off = 32; off > 0; off >>= 1) {
    s += __shfl_down(s, off, 64);
    s2 += __shfl_down(s2, off, 64);
  }
  if (l == 0) {
    const double N = 2048.0 * 64.0;
    double mean = s / N;
    double var = s2 / N - mean * mean;
    stats[g * 2] = (float)mean;
    stats[g * 2 + 1] = (float)(1.0 / sqrt(var + 1e-5));
  }
}

// ---------------- normalize + affine -> bf16 ----------------
__global__ __launch_bounds__(256) void gn_apply(const float* __restrict__ ctx,
                                                const float* __restrict__ stats,
                                                const float* __restrict__ gw,
                                                const float* __restrict__ gb,
                                                unsigned short* __restrict__ outc) {
  int i = blockIdx.x * 256 + threadIdx.x;
  if (i >= 4096 * 768) return;
  int c = i % 768;
  int b = i / (2048 * 768);
  int g = b * 12 + (c >> 6);
  float v = (ctx[i] - stats[2 * g]) * stats[2 * g + 1];
  outc[i] = f2bf(v * gw[c] + gb[c]);
}

extern "C" void kernel_launch(void* const* d_in, const int* in_sizes, int n_in,
                              void* d_out, int out_size, void* d_ws, size_t ws_size,
                              hipStream_t stream) {
  const float* x   = (const float*)d_in[0];
  const float* Wpw = (const float*)d_in[1];
  const float* Wpb = (const float*)d_in[2];
  const float* gnw = (const float*)d_in[3];
  const float* gnb = (const float*)d_in[4];
  const float* ow  = (const float*)d_in[5];
  const float* ob  = (const float*)d_in[6];
  float* out = (float*)d_out;

  char* ws = (char*)d_ws;
  size_t off = 0;
  auto carve = [&](size_t bytes) {
    char* p = ws + off;
    off = (off + bytes + 255) & ~(size_t)255;
    return p;
  };
  unsigned short* xb   = (unsigned short*)carve((size_t)4096 * 768 * 2);
  unsigned short* wb   = (unsigned short*)carve((size_t)5376 * 768 * 2);
  unsigned short* owb  = (unsigned short*)carve((size_t)768 * 768 * 2);
  unsigned short* qkvb = (unsigned short*)carve((size_t)4096 * 5376 * 2);
  unsigned short* ub   = (unsigned short*)carve((size_t)4096 * 768 * 2);
  unsigned short* vtb  = (unsigned short*)carve((size_t)24 * 64 * 2048 * 2);
  unsigned short* utb  = (unsigned short*)carve((size_t)24 * 64 * 2048 * 2);
  float* ctx           = (float*)carve((size_t)4096 * 768 * 4);
  float* partials      = (float*)carve(24 * 32 * 2 * 4);
  float* stats         = (float*)carve(48 * 4);

  cvt_bf16_4<<<3072, 256, 0, stream>>>(x, xb, 4096 * 768);
  cvt_bf16_4<<<4032, 256, 0, stream>>>(Wpw, wb, 5376 * 768);
  cvt_bf16_4<<<576, 256, 0, stream>>>(ow, owb, 768 * 768);

  gemm_nt<true><<<dim3(42, 32), 256, 0, stream>>>(xb, wb, Wpb, qkvb, 4096, 5376, 768);
  transp64<<<dim3(32, 24), 256, 0, stream>>>(qkvb, 5376, 6 * 768, vtb);   // V -> V^T
  pass1<<<dim3(32, 24), 128, 0, stream>>>(qkvb, vtb, ub);
  transp64<<<dim3(32, 24), 256, 0, stream>>>(ub, 768, 0, utb);            // u -> u^T
  pass2<<<dim3(32, 24), 128, 0, stream>>>(qkvb, utb, ctx, partials);
  gn_finalize<<<24, 64, 0, stream>>>(partials, stats);
  gn_apply<<<12288, 256, 0, stream>>>(ctx, stats, gnw, gnb, xb);
  gemm_nt<false><<<dim3(6, 32), 256, 0, stream>>>(xb, owb, ob, out, 4096, 768, 768);
}

// Round 9
// 220.628 us; speedup vs baseline: 1.0933x; 1.0933x over previous
//
#include <hip/hip_runtime.h>
#include <hip/hip_bf16.h>
#include <stdint.h>

// B=2, S=2048, D_MODEL=768, H=12, HD=64, 7*D=5376
typedef short short8 __attribute__((ext_vector_type(8)));
typedef float f32x4 __attribute__((ext_vector_type(4)));
typedef float f32x16 __attribute__((ext_vector_type(16)));
typedef unsigned short u16x4 __attribute__((ext_vector_type(4)));
typedef unsigned uint4v __attribute__((ext_vector_type(4)));

#define MFMA16 __builtin_amdgcn_mfma_f32_16x16x32_bf16
#define MFMA32 __builtin_amdgcn_mfma_f32_32x32x16_bf16

typedef unsigned int __attribute__((address_space(1))) as1_u32;
typedef unsigned int __attribute__((address_space(3))) as3_u32;
#define GLOAD16(gsrc, ldst) \
  __builtin_amdgcn_global_load_lds((const as1_u32*)(gsrc), (as3_u32*)(ldst), 16, 0, 0)

__device__ __forceinline__ unsigned short f2bf(float f) {
  __hip_bfloat16 h = __float2bfloat16(f);
  return *(unsigned short*)&h;
}
__device__ __forceinline__ unsigned pk2(float lo, float hi) {
  return ((unsigned)f2bf(hi) << 16) | (unsigned)f2bf(lo);
}
// vdst.row1 (lanes>=32) <-> vsrc.row0 (lanes<32)
__device__ __forceinline__ void plswap(unsigned &a, unsigned &b) {
  asm volatile("v_permlane32_swap_b32 %0, %1" : "+v"(a), "+v"(b));
}

// Build PV A-fragment for chunk kc2 from swapped-QK accumulator halves.
// acc[sn][reg] holds S^T[s = sn*32 + 8*(reg>>2) + 4*g5 + (reg&3)][t = l31].
__device__ __forceinline__ short8 pv_frag(const f32x16* acc, int kc2) {
  int n = kc2 >> 1, c = kc2 & 1;
  int o0 = 2 * c, o1 = 2 * c + 1;
  unsigned x0 = pk2(acc[n][o0 * 4 + 0], acc[n][o0 * 4 + 1]);
  unsigned x1 = pk2(acc[n][o0 * 4 + 2], acc[n][o0 * 4 + 3]);
  unsigned y0 = pk2(acc[n][o1 * 4 + 0], acc[n][o1 * 4 + 1]);
  unsigned y1 = pk2(acc[n][o1 * 4 + 2], acc[n][o1 * 4 + 3]);
  plswap(x0, y0);
  plswap(x1, y1);
  uint4v fu; fu.x = x0; fu.y = x1; fu.z = y0; fu.w = y1;
  return __builtin_bit_cast(short8, fu);
}

// ---------------- convert f32 -> bf16, 4 elems/thread ----------------
__global__ __launch_bounds__(256) void cvt_bf16_4(const float* __restrict__ in,
                                                  unsigned short* __restrict__ out,
                                                  int n) {
  int i = (blockIdx.x * 256 + threadIdx.x) * 4;
  if (i >= n) return;
  f32x4 v = *(const f32x4*)(in + i);
  u16x4 o;
  o.x = f2bf(v.x); o.y = f2bf(v.y); o.z = f2bf(v.z); o.w = f2bf(v.w);
  *(u16x4*)(out + i) = o;
}

// ---------------- 64x64 head-tile transpose: src[b][s][stride] -> dst[bh][d][2048] ----
__global__ __launch_bounds__(256) void transp64(const unsigned short* __restrict__ src,
                                                int stride, int off,
                                                unsigned short* __restrict__ dst) {
  __shared__ __align__(16) unsigned short t[64 * 64];
  const int tid = threadIdx.x;
  const int tt = blockIdx.x, bh = blockIdx.y;
  const int b = bh / 12, h = bh % 12;
  const unsigned short* sbase = src + (size_t)(b * 2048 + tt * 64) * stride + h * 64 + off;
  for (int it = 0; it < 2; ++it) {
    int slot = it * 256 + tid, s = slot >> 3, j = slot & 7;
    short8 v = *(const short8*)(sbase + (size_t)s * stride + j * 8);
    int phys = (s + 8 * j) & 63;
    for (int e = 0; e < 8; ++e)
      t[(j * 8 + e) * 64 + phys] = ((unsigned short*)&v)[e];
  }
  __syncthreads();
  unsigned short* dbase = dst + (size_t)bh * 64 * 2048 + tt * 64;
  for (int it = 0; it < 2; ++it) {
    int slot = it * 256 + tid, d = slot >> 3, c = slot & 7;
    int pc = (c + (d >> 3)) & 7;
    short8 v = *(const short8*)(t + d * 64 + pc * 8);
    *(short8*)(dbase + (size_t)d * 2048 + c * 8) = v;
  }
}

// ---------------- GEMM: C[M][N] = A[M][K] * B[N][K]^T + bias ----------------
template <bool OUT_BF16>
__global__ __launch_bounds__(256) void gemm_nt(const unsigned short* __restrict__ A,
                                               const unsigned short* __restrict__ Bm,
                                               const float* __restrict__ bias,
                                               void* __restrict__ Cout,
                                               int M, int N, int K) {
  __shared__ __align__(16) char smem[32768];
  char* As = smem;
  char* Bs = smem + 16384;
  const int tid = threadIdx.x;
  const int w = tid >> 6, l = tid & 63;
  const int wm = w >> 1, wn = w & 1;
  const int Row0 = blockIdx.y * 128, Col0 = blockIdx.x * 128;

  f32x4 z; z.x = 0.f; z.y = 0.f; z.z = 0.f; z.w = 0.f;
  f32x4 acc[4][4];
  for (int m = 0; m < 4; ++m)
    for (int n = 0; n < 4; ++n) acc[m][n] = z;

  for (int k0 = 0; k0 < K; k0 += 64) {
    for (int it = 0; it < 4; ++it) {
      int slot = it * 256 + tid;
      int row = slot >> 3, j = slot & 7;
      int gc = j ^ (row & 7);
      GLOAD16(A + (size_t)(Row0 + row) * K + k0 + gc * 8, As + slot * 16);
      GLOAD16(Bm + (size_t)(Col0 + row) * K + k0 + gc * 8, Bs + slot * 16);
    }
    __syncthreads();
    for (int kc = 0; kc < 2; ++kc) {
      int c = (l >> 4) + 4 * kc;
      short8 af[4], bf[4];
      for (int m = 0; m < 4; ++m) {
        int t = wm * 64 + m * 16 + (l & 15);
        af[m] = *(const short8*)(As + t * 128 + ((c ^ (t & 7)) * 16));
      }
      for (int n = 0; n < 4; ++n) {
        int t = wn * 64 + n * 16 + (l & 15);
        bf[n] = *(const short8*)(Bs + t * 128 + ((c ^ (t & 7)) * 16));
      }
      for (int m = 0; m < 4; ++m)
        for (int n = 0; n < 4; ++n)
          acc[m][n] = MFMA16(af[m], bf[n], acc[m][n], 0, 0, 0);
    }
    __syncthreads();
  }
  for (int n = 0; n < 4; ++n) {
    int col = Col0 + wn * 64 + n * 16 + (l & 15);
    float bv = bias[col];
    for (int m = 0; m < 4; ++m) {
      int rbase = Row0 + wm * 64 + m * 16 + (l >> 4) * 4;
      for (int r = 0; r < 4; ++r) {
        float v = acc[m][n][r] + bv;
        size_t idx = (size_t)(rbase + r) * N + col;
        if (OUT_BF16) ((unsigned short*)Cout)[idx] = f2bf(v);
        else          ((float*)Cout)[idx] = v;
      }
    }
  }
}

// ---------------- pass1 (split-s, 8 waves, T14 reg-staged pipeline) -----------------
// grid (16 tt of 128 t-rows, 24 bh). 512 thr = 2 s-halves x 4 t-subs x 32 t-rows.
__global__ __launch_bounds__(512, 2) void pass1(const unsigned short* __restrict__ qkv,
                                                const unsigned short* __restrict__ vt,
                                                unsigned short* __restrict__ u) {
  __shared__ __align__(16) char smem[49152];
  const int tid = threadIdx.x, w = tid >> 6, l = tid & 63;
  const int sh = w >> 2, wi = w & 3;       // s-half, t-subtile
  const int tidh = tid & 255;
  const int g5 = l >> 5, l31 = l & 31;
  const int tt = blockIdx.x, bh = blockIdx.y;
  const int b = bh / 12, h = bh % 12;
  char* half = smem + sh * 24576;          // K1 8K | K2 8K | V 8K

  // Q fragments (B-operand of swapped QK): col t = l31, k-d = kc*16 + g5*8
  const int tg = tt * 128 + wi * 32 + l31;
  const unsigned short* qrow = qkv + (size_t)(b * 2048 + tg) * 5376 + h * 64;
  short8 q1f[4], q2f[4];
#pragma unroll
  for (int kc = 0; kc < 4; ++kc) {
    int d = kc * 16 + g5 * 8;
    q1f[kc] = *(const short8*)(qrow + 0 * 768 + d);
    q2f[kc] = *(const short8*)(qrow + 2 * 768 + d);
  }

  f32x16 z16;
#pragma unroll
  for (int i = 0; i < 16; ++i) z16[i] = 0.f;
  f32x16 t1a[2], t2a[2];
  t1a[0] = z16; t1a[1] = z16; t2a[0] = z16; t2a[1] = z16;

  // T14 register staging: 6 x 16B per thread (K1 x2, K2 x2, V x2)
  uint4v st[6];
  auto LOAD = [&](int s0) {
#pragma unroll
    for (int it = 0; it < 2; ++it) {
      int slot = it * 256 + tidh, row = slot >> 3, j = slot & 7, gc = j ^ (row & 7);
      const unsigned short* ks =
          qkv + (size_t)(b * 2048 + s0 + row) * 5376 + h * 64 + 768 + gc * 8;
      st[it]     = *(const uint4v*)ks;
      st[2 + it] = *(const uint4v*)(ks + 2 * 768);
      st[4 + it] = *(const uint4v*)(vt + (size_t)(bh * 64 + row) * 2048 + s0 + gc * 8);
    }
  };
  auto WRITE = [&]() {
#pragma unroll
    for (int it = 0; it < 2; ++it) {
      int slot = it * 256 + tidh;
      *(uint4v*)(half + slot * 16)         = st[it];
      *(uint4v*)(half + 8192 + slot * 16)  = st[2 + it];
      *(uint4v*)(half + 16384 + slot * 16) = st[4 + it];
    }
  };

  LOAD(sh * 1024);
  for (int si = 0; si < 16; ++si) {
    __syncthreads();                       // all waves done reading buf
    WRITE();
    __syncthreads();                       // writes visible to the half's waves
    if (si < 15) LOAD(sh * 1024 + (si + 1) * 64);   // fly during compute

    const char* Ks0 = half;
    const char* Ks1 = half + 8192;
    const char* Vs  = half + 16384;

    // QK swapped: S^T = K @ Q  (rows = s, cols = t)
    f32x16 a1t[2], a2t[2];
    a1t[0] = z16; a1t[1] = z16; a2t[0] = z16; a2t[1] = z16;
#pragma unroll
    for (int kc = 0; kc < 4; ++kc)
#pragma unroll
      for (int sn = 0; sn < 2; ++sn) {
        int srow = sn * 32 + l31;
        int off = srow * 128 + (((kc * 2 + g5) ^ (l31 & 7)) * 16);
        a1t[sn] = MFMA32(*(const short8*)(Ks0 + off), q1f[kc], a1t[sn], 0, 0, 0);
        a2t[sn] = MFMA32(*(const short8*)(Ks1 + off), q2f[kc], a2t[sn], 0, 0, 0);
      }

    // PV: t1 += S @ V, t2 += S2 @ V; A-fragments built in-register
#pragma unroll
    for (int kc2 = 0; kc2 < 4; ++kc2) {
      short8 pa1 = pv_frag(a1t, kc2);
      short8 pa2 = pv_frag(a2t, kc2);
#pragma unroll
      for (int dn = 0; dn < 2; ++dn) {
        int drow = dn * 32 + l31;
        short8 vf = *(const short8*)(Vs + drow * 128 + (((kc2 * 2 + g5) ^ (l31 & 7)) * 16));
        t1a[dn] = MFMA32(pa1, vf, t1a[dn], 0, 0, 0);
        t2a[dn] = MFMA32(pa2, vf, t2a[dn], 0, 0, 0);
      }
    }
  }
  __syncthreads();

  // combine halves through LDS: conflict-free chunk layout (c*1024 + l*16 bytes)
  char* comb = smem + wi * 8192;
  // round A: t1
  if (sh == 1) {
#pragma unroll
    for (int c = 0; c < 8; ++c) {
      f32x4 q;
      q.x = t1a[c >> 2][(c & 3) * 4 + 0];
      q.y = t1a[c >> 2][(c & 3) * 4 + 1];
      q.z = t1a[c >> 2][(c & 3) * 4 + 2];
      q.w = t1a[c >> 2][(c & 3) * 4 + 3];
      *(f32x4*)(comb + c * 1024 + l * 16) = q;
    }
  }
  __syncthreads();
  if (sh == 0) {
#pragma unroll
    for (int c = 0; c < 8; ++c) {
      f32x4 q = *(const f32x4*)(comb + c * 1024 + l * 16);
      t1a[c >> 2][(c & 3) * 4 + 0] += q.x;
      t1a[c >> 2][(c & 3) * 4 + 1] += q.y;
      t1a[c >> 2][(c & 3) * 4 + 2] += q.z;
      t1a[c >> 2][(c & 3) * 4 + 3] += q.w;
    }
  }
  __syncthreads();
  // round B: t2
  if (sh == 1) {
#pragma unroll
    for (int c = 0; c < 8; ++c) {
      f32x4 q;
      q.x = t2a[c >> 2][(c & 3) * 4 + 0];
      q.y = t2a[c >> 2][(c & 3) * 4 + 1];
      q.z = t2a[c >> 2][(c & 3) * 4 + 2];
      q.w = t2a[c >> 2][(c & 3) * 4 + 3];
      *(f32x4*)(comb + c * 1024 + l * 16) = q;
    }
  }
  __syncthreads();
  if (sh == 0) {
#pragma unroll
    for (int c = 0; c < 8; ++c) {
      f32x4 q = *(const f32x4*)(comb + c * 1024 + l * 16);
      t2a[c >> 2][(c & 3) * 4 + 0] += q.x;
      t2a[c >> 2][(c & 3) * 4 + 1] += q.y;
      t2a[c >> 2][(c & 3) * 4 + 2] += q.z;
      t2a[c >> 2][(c & 3) * 4 + 3] += q.w;
    }
    // u = silu(t1) * t2
#pragma unroll
    for (int dn = 0; dn < 2; ++dn)
#pragma unroll
      for (int r = 0; r < 16; ++r) {
        int t = tt * 128 + wi * 32 + (r & 3) + 8 * (r >> 2) + 4 * g5;
        int d = dn * 32 + l31;
        float x1 = t1a[dn][r], x2 = t2a[dn][r];
        float uu = (x1 / (1.f + expf(-x1))) * x2;
        u[(size_t)(b * 2048 + t) * 768 + h * 64 + d] = f2bf(uu);
      }
  }
}

// ---------------- pass2 (split-s, 8 waves, T14 reg-staged): ctx = a3 @ u + GN ------
__global__ __launch_bounds__(512, 2) void pass2(const unsigned short* __restrict__ qkv,
                                                const unsigned short* __restrict__ ut,
                                                float* __restrict__ ctx,
                                                float* __restrict__ partials) {
  __shared__ __align__(16) char smem[32768];
  const int tid = threadIdx.x, w = tid >> 6, l = tid & 63;
  const int sh = w >> 2, wi = w & 3;
  const int tidh = tid & 255;
  const int g5 = l >> 5, l31 = l & 31;
  const int tt = blockIdx.x, bh = blockIdx.y;
  const int b = bh / 12, h = bh % 12;
  char* half = smem + sh * 16384;          // K3 8K | U 8K

  const int tg = tt * 128 + wi * 32 + l31;
  const unsigned short* qrow = qkv + (size_t)(b * 2048 + tg) * 5376 + h * 64;
  short8 q3f[4];
#pragma unroll
  for (int kc = 0; kc < 4; ++kc)
    q3f[kc] = *(const short8*)(qrow + 4 * 768 + kc * 16 + g5 * 8);

  f32x16 z16;
#pragma unroll
  for (int i = 0; i < 16; ++i) z16[i] = 0.f;
  f32x16 ca[2];
  ca[0] = z16; ca[1] = z16;

  uint4v st[4];
  auto LOAD = [&](int s0) {
#pragma unroll
    for (int it = 0; it < 2; ++it) {
      int slot = it * 256 + tidh, row = slot >> 3, j = slot & 7, gc = j ^ (row & 7);
      st[it]     = *(const uint4v*)(qkv + (size_t)(b * 2048 + s0 + row) * 5376 +
                                    h * 64 + 5 * 768 + gc * 8);
      st[2 + it] = *(const uint4v*)(ut + (size_t)(bh * 64 + row) * 2048 + s0 + gc * 8);
    }
  };
  auto WRITE = [&]() {
#pragma unroll
    for (int it = 0; it < 2; ++it) {
      int slot = it * 256 + tidh;
      *(uint4v*)(half + slot * 16)        = st[it];
      *(uint4v*)(half + 8192 + slot * 16) = st[2 + it];
    }
  };

  LOAD(sh * 1024);
  for (int si = 0; si < 16; ++si) {
    __syncthreads();
    WRITE();
    __syncthreads();
    if (si < 15) LOAD(sh * 1024 + (si + 1) * 64);

    const char* Ks = half;
    const char* Us = half + 8192;

    f32x16 a3t[2];
    a3t[0] = z16; a3t[1] = z16;
#pragma unroll
    for (int kc = 0; kc < 4; ++kc)
#pragma unroll
      for (int sn = 0; sn < 2; ++sn) {
        int srow = sn * 32 + l31;
        int off = srow * 128 + (((kc * 2 + g5) ^ (l31 & 7)) * 16);
        a3t[sn] = MFMA32(*(const short8*)(Ks + off), q3f[kc], a3t[sn], 0, 0, 0);
      }
#pragma unroll
    for (int kc2 = 0; kc2 < 4; ++kc2) {
      short8 pa = pv_frag(a3t, kc2);
#pragma unroll
      for (int dn = 0; dn < 2; ++dn) {
        int drow = dn * 32 + l31;
        short8 uf = *(const short8*)(Us + drow * 128 + (((kc2 * 2 + g5) ^ (l31 & 7)) * 16));
        ca[dn] = MFMA32(pa, uf, ca[dn], 0, 0, 0);
      }
    }
  }
  __syncthreads();

  // combine halves
  char* comb = smem + wi * 8192;
  if (sh == 1) {
#pragma unroll
    for (int c = 0; c < 8; ++c) {
      f32x4 q;
      q.x = ca[c >> 2][(c & 3) * 4 + 0];
      q.y = ca[c >> 2][(c & 3) * 4 + 1];
      q.z = ca[c >> 2][(c & 3) * 4 + 2];
      q.w = ca[c >> 2][(c & 3) * 4 + 3];
      *(f32x4*)(comb + c * 1024 + l * 16) = q;
    }
  }
  __syncthreads();
  float psum = 0.f, psum2 = 0.f;
  if (sh == 0) {
#pragma unroll
    for (int c = 0; c < 8; ++c) {
      f32x4 q = *(const f32x4*)(comb + c * 1024 + l * 16);
      ca[c >> 2][(c & 3) * 4 + 0] += q.x;
      ca[c >> 2][(c & 3) * 4 + 1] += q.y;
      ca[c >> 2][(c & 3) * 4 + 2] += q.z;
      ca[c >> 2][(c & 3) * 4 + 3] += q.w;
    }
#pragma unroll
    for (int dn = 0; dn < 2; ++dn)
#pragma unroll
      for (int r = 0; r < 16; ++r) {
        int t = tt * 128 + wi * 32 + (r & 3) + 8 * (r >> 2) + 4 * g5;
        int d = dn * 32 + l31;
        float v = ca[dn][r];
        ctx[(size_t)(b * 2048 + t) * 768 + h * 64 + d] = v;
        psum += v; psum2 += v * v;
      }
  }
  __syncthreads();

  float* red = (float*)smem;
  red[tid] = psum; red[512 + tid] = psum2;
  __syncthreads();
  for (int st2 = 256; st2 > 0; st2 >>= 1) {
    if (tid < st2) {
      red[tid] += red[tid + st2];
      red[512 + tid] += red[512 + tid + st2];
    }
    __syncthreads();
  }
  if (tid == 0) {
    partials[(bh * 16 + tt) * 2] = red[0];
    partials[(bh * 16 + tt) * 2 + 1] = red[512];
  }
}

// ---------------- finalize GN stats from 16 partials per group ----------------
__global__ __launch_bounds__(64) void gn_finalize(const float* __restrict__ partials,
                                                  float* __restrict__ stats) {
  const int g = blockIdx.x;
  const int l = threadIdx.x;
  double s = 0.0, s2 = 0.0;
  if (l < 16) {
    s = (double)partials[(g * 16 + l) * 2];
    s2 = (double)partials[(g * 16 + l) * 2 + 1];
  }
  for (int off = 32; off > 0; off >>= 1) {
    s += __shfl_down(s, off, 64);
    s2 += __shfl_down(s2, off, 64);
  }
  if (l == 0) {
    const double N = 2048.0 * 64.0;
    double mean = s / N;
    double var = s2 / N - mean * mean;
    stats[g * 2] = (float)mean;
    stats[g * 2 + 1] = (float)(1.0 / sqrt(var + 1e-5));
  }
}

// ---------------- normalize + affine -> bf16 ----------------
__global__ __launch_bounds__(256) void gn_apply(const float* __restrict__ ctx,
                                                const float* __restrict__ stats,
                                                const float* __restrict__ gw,
                                                const float* __restrict__ gb,
                                                unsigned short* __restrict__ outc) {
  int i = blockIdx.x * 256 + threadIdx.x;
  if (i >= 4096 * 768) return;
  int c = i % 768;
  int b = i / (2048 * 768);
  int g = b * 12 + (c >> 6);
  float v = (ctx[i] - stats[2 * g]) * stats[2 * g + 1];
  outc[i] = f2bf(v * gw[c] + gb[c]);
}

extern "C" void kernel_launch(void* const* d_in, const int* in_sizes, int n_in,
                              void* d_out, int out_size, void* d_ws, size_t ws_size,
                              hipStream_t stream) {
  const float* x   = (const float*)d_in[0];
  const float* Wpw = (const float*)d_in[1];
  const float* Wpb = (const float*)d_in[2];
  const float* gnw = (const float*)d_in[3];
  const float* gnb = (const float*)d_in[4];
  const float* ow  = (const float*)d_in[5];
  const float* ob  = (const float*)d_in[6];
  float* out = (float*)d_out;

  char* ws = (char*)d_ws;
  size_t off = 0;
  auto carve = [&](size_t bytes) {
    char* p = ws + off;
    off = (off + bytes + 255) & ~(size_t)255;
    return p;
  };
  unsigned short* xb   = (unsigned short*)carve((size_t)4096 * 768 * 2);
  unsigned short* wb   = (unsigned short*)carve((size_t)5376 * 768 * 2);
  unsigned short* owb  = (unsigned short*)carve((size_t)768 * 768 * 2);
  unsigned short* qkvb = (unsigned short*)carve((size_t)4096 * 5376 * 2);
  unsigned short* ub   = (unsigned short*)carve((size_t)4096 * 768 * 2);
  unsigned short* vtb  = (unsigned short*)carve((size_t)24 * 64 * 2048 * 2);
  unsigned short* utb  = (unsigned short*)carve((size_t)24 * 64 * 2048 * 2);
  float* ctx           = (float*)carve((size_t)4096 * 768 * 4);
  float* partials      = (float*)carve(24 * 16 * 2 * 4);
  float* stats         = (float*)carve(48 * 4);

  cvt_bf16_4<<<3072, 256, 0, stream>>>(x, xb, 4096 * 768);
  cvt_bf16_4<<<4032, 256, 0, stream>>>(Wpw, wb, 5376 * 768);
  cvt_bf16_4<<<576, 256, 0, stream>>>(ow, owb, 768 * 768);

  gemm_nt<true><<<dim3(42, 32), 256, 0, stream>>>(xb, wb, Wpb, qkvb, 4096, 5376, 768);
  transp64<<<dim3(32, 24), 256, 0, stream>>>(qkvb, 5376, 6 * 768, vtb);   // V -> V^T
  pass1<<<dim3(16, 24), 512, 0, stream>>>(qkvb, vtb, ub);
  transp64<<<dim3(32, 24), 256, 0, stream>>>(ub, 768, 0, utb);            // u -> u^T
  pass2<<<dim3(16, 24), 512, 0, stream>>>(qkvb, utb, ctx, partials);
  gn_finalize<<<24, 64, 0, stream>>>(partials, stats);
  gn_apply<<<12288, 256, 0, stream>>>(ctx, stats, gnw, gnb, xb);
  gemm_nt<false><<<dim3(6, 32), 256, 0, stream>>>(xb, owb, ob, out, 4096, 768, 768);
}